// Round 15
// baseline (111.097 us; speedup 1.0000x reference)
//
#include <hip/hip_runtime.h>
#include <hip/hip_bf16.h>

typedef __bf16 bf16x8 __attribute__((ext_vector_type(8)));
typedef __bf16 bf16x4 __attribute__((ext_vector_type(4)));
typedef float f32x4 __attribute__((ext_vector_type(4)));

#define MFMA16(a,b,c) __builtin_amdgcn_mfma_f32_16x16x32_bf16(a, b, c, 0, 0, 0)

typedef const __attribute__((address_space(1))) void* gas_t;
typedef __attribute__((address_space(3))) void* las_t;

__device__ inline void gload16(const __bf16* g, __bf16* lds) {
  __builtin_amdgcn_global_load_lds((gas_t)g, (las_t)lds, 16, 0, 0);
}

// ---------------- prep: transpose + cvt W_qkv, W_out ----------------
__device__ inline void transpose_body(const float* __restrict__ in, __bf16* __restrict__ out,
                                      int R, int C, int tile, int tid, float (*t)[65]) {
  const int tilesC = C >> 6;
  const int tc = tile % tilesC, tr = tile / tilesC;
  const int r0 = tr << 6, c0 = tc << 6;
  const int ri = tid >> 2, cq = (tid & 3) << 4;
#pragma unroll
  for (int e = 0; e < 16; e += 4) {
    float4 v = *reinterpret_cast<const float4*>(&in[(size_t)(r0 + ri) * C + c0 + cq + e]);
    t[ri][cq + e]     = v.x;
    t[ri][cq + e + 1] = v.y;
    t[ri][cq + e + 2] = v.z;
    t[ri][cq + e + 3] = v.w;
  }
  __syncthreads();
  const int co = tid >> 2, rq = (tid & 3) << 4;
  __attribute__((aligned(16))) __bf16 buf[16];
#pragma unroll
  for (int e = 0; e < 16; e++) buf[e] = (__bf16)t[rq + e][co];
  *reinterpret_cast<bf16x8*>(&out[(size_t)(c0 + co) * R + r0 + rq])     = *reinterpret_cast<bf16x8*>(&buf[0]);
  *reinterpret_cast<bf16x8*>(&out[(size_t)(c0 + co) * R + r0 + rq + 8]) = *reinterpret_cast<bf16x8*>(&buf[8]);
}

__global__ __launch_bounds__(256) void prep(const float* __restrict__ Wqkv,
                                            const float* __restrict__ Wout,
                                            __bf16* __restrict__ Wqt,
                                            __bf16* __restrict__ Wot) {
  __shared__ float t[64][65];
  const int bid = blockIdx.x, tid = threadIdx.x;
  if (bid < 192) transpose_body(Wqkv, Wqt, 512, 1536, bid, tid, t);
  else           transpose_body(Wout, Wot, 512, 512, bid - 192, tid, t);
}

// ---------------- GEMM: C[M][N] = A[M][K] * Bt[N][K]^T (pure compute) ----------------
template <typename AT, typename OT>
__global__ __launch_bounds__(256) void gemm_bt(const AT* __restrict__ A,
                                               const __bf16* __restrict__ Bt,
                                               OT* __restrict__ C, int M, int N, int K) {
  constexpr bool AF32 = (sizeof(AT) == 4);
  constexpr int ASZ = AF32 ? 128 * 72 * 2 : 128 * 64 * 2;
  __shared__ __align__(16) char asbuf[ASZ];
  __shared__ __align__(16) __bf16 BsL[128 * 64];
  const int tid = threadIdx.x;

  const int wave = tid >> 6, lane = tid & 63;
  const int c = lane & 15, q4 = lane >> 4;
  const int bm = blockIdx.y << 7, bn = blockIdx.x << 7;
  const int wm = (wave >> 1) << 6, wn = (wave & 1) << 6;
  f32x4 acc[4][4];
#pragma unroll
  for (int m = 0; m < 4; m++)
#pragma unroll
    for (int n = 0; n < 4; n++)
#pragma unroll
      for (int e = 0; e < 4; e++) acc[m][n][e] = 0.f;

  __bf16 (*AsP)[72] = (AF32 ? (__bf16 (*)[72])asbuf : nullptr);
  __bf16* AsL = (__bf16*)asbuf;

  const int srow8 = lane >> 3;
  const int sseg  = lane & 7;
  auto stage_async = [&](const __bf16* src, __bf16* dst, int rowBase, int k0) {
#pragma unroll
    for (int i = 0; i < 4; i++) {
      const int rb = (wave << 5) + (i << 3);
      const int rr = rb + srow8;
      const int cs = sseg ^ (rr & 7);
      gload16(src + (size_t)(rowBase + rr) * K + k0 + cs * 8, dst + rb * 64);
    }
  };

  const int srow = tid >> 1, scol = (tid & 1) << 5;
  bf16x8 av[4];
  auto loadA_f32 = [&](int k0) {
    const AT* ag = A + (size_t)(bm + srow) * K + k0 + scol;
#pragma unroll
    for (int r = 0; r < 4; r++) {
      float4 lo = *reinterpret_cast<const float4*>(ag + r * 8);
      float4 hi = *reinterpret_cast<const float4*>(ag + r * 8 + 4);
      bf16x8 v;
      v[0] = (__bf16)lo.x; v[1] = (__bf16)lo.y; v[2] = (__bf16)lo.z; v[3] = (__bf16)lo.w;
      v[4] = (__bf16)hi.x; v[5] = (__bf16)hi.y; v[6] = (__bf16)hi.z; v[7] = (__bf16)hi.w;
      av[r] = v;
    }
  };

  if constexpr (AF32) loadA_f32(0);

  for (int k0 = 0; k0 < K; k0 += 64) {
    __syncthreads();
    if constexpr (AF32) {
#pragma unroll
      for (int r = 0; r < 4; r++)
        *reinterpret_cast<bf16x8*>(&AsP[srow][scol + r * 8]) = av[r];
    } else {
      stage_async((const __bf16*)A, AsL, bm, k0);
    }
    stage_async(Bt, BsL, bn, k0);
    __syncthreads();
    if constexpr (AF32) {
      if (k0 + 64 < K) loadA_f32(k0 + 64);
    }
#pragma unroll
    for (int ks = 0; ks < 2; ks++) {
      const int kk = ks * 32 + q4 * 8;
      bf16x8 af[4], bfv[4];
#pragma unroll
      for (int m = 0; m < 4; m++) {
        const int row = wm + m * 16 + c;
        if constexpr (AF32) af[m] = *reinterpret_cast<const bf16x8*>(&AsP[row][kk]);
        else af[m] = *reinterpret_cast<const bf16x8*>(&AsL[row * 64 + ((ks * 4 + q4) ^ (row & 7)) * 8]);
      }
#pragma unroll
      for (int n = 0; n < 4; n++) {
        const int row = wn + n * 16 + c;
        bfv[n] = *reinterpret_cast<const bf16x8*>(&BsL[row * 64 + ((ks * 4 + q4) ^ (row & 7)) * 8]);
      }
#pragma unroll
      for (int m = 0; m < 4; m++)
#pragma unroll
        for (int n = 0; n < 4; n++) acc[m][n] = MFMA16(af[m], bfv[n], acc[m][n]);
    }
  }
#pragma unroll
  for (int m = 0; m < 4; m++)
#pragma unroll
    for (int n = 0; n < 4; n++)
#pragma unroll
      for (int r2 = 0; r2 < 4; r2++) {
        const int row = bm + wm + m * 16 + q4 * 4 + r2;
        const int col = bn + wn + n * 16 + c;
        C[(size_t)row * N + col] = (OT)acc[m][n][r2];
      }
}

// -------- fused attention, wave-per-rowgroup; block streams its full 64-row stripe ------
// grid: (32, 16). Each block writes its entire contiguous 512KB attn region (zeros+band).
__global__ __launch_bounds__(256) void attn_fused(const __bf16* __restrict__ QKV,
                                                  float* __restrict__ attn,
                                                  __bf16* __restrict__ AO) {
  __shared__ __align__(16) char smem[64 * 328 * 2];  // 41.98 KB, overlaid
  __bf16 (*KV)[64][72] = reinterpret_cast<__bf16 (*)[64][72]>(smem);          // [2][64][72]
  __bf16 (*Pw)[16][72] = reinterpret_cast<__bf16 (*)[16][72]>(smem + 18432);  // [4][16][72]
  __bf16 (*Ps)[328]    = reinterpret_cast<__bf16 (*)[328]>(smem);             // [64][328]
  const int tid = threadIdx.x;

  const int qt = blockIdx.x, bh = blockIdx.y;
  const int b = bh >> 3, h = bh & 7;
  const int qi0 = qt << 6;
  const int wave = tid >> 6, lane = tid & 63;
  const int c = lane & 15, q4 = lane >> 4;
  const int base = b * 2048;
  const int r = tid >> 2, qq = (tid & 3) << 4;

  // Q fragments direct to registers
  bf16x8 qf0, qf1;
  {
    const __bf16* s = QKV + (size_t)(base + qi0 + wave * 16 + c) * 1536 + h * 64 + q4 * 8;
    qf0 = *reinterpret_cast<const bf16x8*>(s);
    qf1 = *reinterpret_cast<const bf16x8*>(s + 32);
  }

  f32x4 acc[5][4];  // [t][ct]: rows w*16+q4*4+r2, cols (qt-4+t)*64 + ct*16 + c
#pragma unroll
  for (int t = 0; t < 5; t++)
#pragma unroll
    for (int ct = 0; ct < 4; ct++)
#pragma unroll
      for (int e = 0; e < 4; e++) acc[t][ct][e] = 0.f;

  const int tfirst = qt >= 4 ? 0 : 4 - qt;
  bf16x8 kv0, kv1;
  {  // prologue K load
    const __bf16* s = QKV + (size_t)(base + ((qt - 4 + tfirst) << 6) + r) * 1536 + 512 + h * 64 + qq;
    kv0 = *reinterpret_cast<const bf16x8*>(s);
    kv1 = *reinterpret_cast<const bf16x8*>(s + 8);
  }
  int cur = 0;
#pragma unroll
  for (int t = 0; t < 5; t++) {
    if (qt - 4 + t < 0) continue;  // block-uniform
    *reinterpret_cast<bf16x8*>(&KV[cur][r][qq]) = kv0;
    *reinterpret_cast<bf16x8*>(&KV[cur][r][qq + 8]) = kv1;
    if (t < 4) {  // prefetch next K tile; completes under MFMA
      const __bf16* s = QKV + (size_t)(base + ((qt - 3 + t) << 6) + r) * 1536 + 512 + h * 64 + qq;
      kv0 = *reinterpret_cast<const bf16x8*>(s);
      kv1 = *reinterpret_cast<const bf16x8*>(s + 8);
    }
    __syncthreads();
#pragma unroll
    for (int ks = 0; ks < 2; ks++) {
      const int kk = ks * 32 + q4 * 8;
      const bf16x8 af = ks ? qf1 : qf0;
#pragma unroll
      for (int ct = 0; ct < 4; ct++) {
        bf16x8 bfr = *reinterpret_cast<const bf16x8*>(&KV[cur][ct * 16 + c][kk]);
        acc[t][ct] = MFMA16(af, bfr, acc[t][ct]);
      }
    }
    cur ^= 1;
  }

  // mask + scale (in-register)
  const float scale = 0.125f;
  const int igBase = qi0 + wave * 16 + q4 * 4;
#pragma unroll
  for (int t = 0; t < 5; t++) {
#pragma unroll
    for (int ct = 0; ct < 4; ct++) {
      const int jb = ((qt - 4 + t) << 6) + ct * 16 + c;
#pragma unroll
      for (int r2 = 0; r2 < 4; r2++) {
        const int ig = igBase + r2;
        const bool valid = (jb >= 0) && (jb <= ig) && (jb >= ig - 255);
        acc[t][ct][r2] = valid ? acc[t][ct][r2] * scale : -1e30f;
      }
    }
  }

  // in-wave softmax (shfl_xor 8,4,2,1 within 16-lane groups)
  float pm[4];
#pragma unroll
  for (int r2 = 0; r2 < 4; r2++) {
    float v = acc[0][0][r2];
#pragma unroll
    for (int t = 0; t < 5; t++)
#pragma unroll
      for (int ct = 0; ct < 4; ct++) v = fmaxf(v, acc[t][ct][r2]);
    pm[r2] = v;
  }
#pragma unroll
  for (int off = 8; off >= 1; off >>= 1)
#pragma unroll
    for (int r2 = 0; r2 < 4; r2++) pm[r2] = fmaxf(pm[r2], __shfl_xor(pm[r2], off, 64));

  float ps[4] = {0.f, 0.f, 0.f, 0.f};
#pragma unroll
  for (int t = 0; t < 5; t++)
#pragma unroll
    for (int ct = 0; ct < 4; ct++)
#pragma unroll
      for (int r2 = 0; r2 < 4; r2++) {
        float p = __expf(acc[t][ct][r2] - pm[r2]);
        acc[t][ct][r2] = p;
        ps[r2] += p;
      }
#pragma unroll
  for (int off = 8; off >= 1; off >>= 1)
#pragma unroll
    for (int r2 = 0; r2 < 4; r2++) ps[r2] += __shfl_xor(ps[r2], off, 64);

#pragma unroll
  for (int r2 = 0; r2 < 4; r2++) ps[r2] = 1.0f / ps[r2];
#pragma unroll
  for (int t = 0; t < 5; t++)
#pragma unroll
    for (int ct = 0; ct < 4; ct++)
#pragma unroll
      for (int r2 = 0; r2 < 4; r2++) acc[t][ct][r2] *= ps[r2];

  __syncthreads();  // guard KV handoff: all QK reads done before PV staging overwrites

  // ---------------- PV phase: O = P @ V ----------------
  f32x4 o[4];
#pragma unroll
  for (int n = 0; n < 4; n++)
#pragma unroll
    for (int e = 0; e < 4; e++) o[n][e] = 0.f;

  const int jv = tid >> 2, dqa = tid & 3;
  bf16x8 vr0, vr1;
  {  // prologue V load
    const __bf16* s = QKV + (size_t)(base + ((qt - 4 + tfirst) << 6) + jv) * 1536 + 1024 + h * 64;
    vr0 = *reinterpret_cast<const bf16x8*>(s + dqa * 8);
    vr1 = *reinterpret_cast<const bf16x8*>(s + (dqa + 4) * 8);
  }
  int pcur = 0;
#pragma unroll
  for (int t = 0; t < 5; t++) {
    if (qt - 4 + t < 0) continue;
    // P tile -> wave-private LDS (same-wave, no barrier)
#pragma unroll
    for (int ct = 0; ct < 4; ct++)
#pragma unroll
      for (int r2 = 0; r2 < 4; r2++)
        Pw[wave][q4 * 4 + r2][ct * 16 + c] = (__bf16)acc[t][ct][r2];
    // V regs -> LDS transposed (shared)
#pragma unroll
    for (int e = 0; e < 8; e++) {
      KV[pcur][dqa * 8 + e][jv] = vr0[e];
      KV[pcur][(dqa + 4) * 8 + e][jv] = vr1[e];
    }
    if (t < 4) {  // prefetch next V tile
      const __bf16* s = QKV + (size_t)(base + ((qt - 3 + t) << 6) + jv) * 1536 + 1024 + h * 64;
      vr0 = *reinterpret_cast<const bf16x8*>(s + dqa * 8);
      vr1 = *reinterpret_cast<const bf16x8*>(s + (dqa + 4) * 8);
    }
    __syncthreads();
#pragma unroll
    for (int ks = 0; ks < 2; ks++) {
      const int kk = ks * 32 + q4 * 8;
      bf16x8 af = *reinterpret_cast<const bf16x8*>(&Pw[wave][c][kk]);
#pragma unroll
      for (int n = 0; n < 4; n++) {
        bf16x8 bfr = *reinterpret_cast<const bf16x8*>(&KV[pcur][n * 16 + c][kk]);
        o[n] = MFMA16(af, bfr, o[n]);
      }
    }
    pcur ^= 1;
  }

  // ---------------- AO stores from registers (independent of LDS) ----------------
#pragma unroll
  for (int n = 0; n < 4; n++)
#pragma unroll
    for (int r2 = 0; r2 < 4; r2++) {
      const int i = igBase + r2;
      const int d = n * 16 + c;
      AO[(size_t)(base + i) * 512 + h * 64 + d] = (__bf16)o[n][r2];
    }

  // ---------------- epilogue: stream the full 64-row stripe (zeros + band) ----------
  __syncthreads();  // all PV reads of KV/Pw done before Ps overlay
  // normalized P -> Ps[64][328] bf16 (masked in-band entries are exactly 0)
#pragma unroll
  for (int t = 0; t < 5; t++) {
    if (qt - 4 + t < 0) continue;
#pragma unroll
    for (int ct = 0; ct < 4; ct++)
#pragma unroll
      for (int r2 = 0; r2 < 4; r2++)
        Ps[wave * 16 + q4 * 4 + r2][t * 64 + ct * 16 + c] = (__bf16)acc[t][ct][r2];
  }
  __syncthreads();

  // stream 64 rows x 2048 cols: lane-consecutive f32x4 NT stores (1KB/wave-instr)
  const int ofs = (qt - 4) << 6;  // global col of Ps local col 0 (may be negative)
  float* tilebase = attn + ((size_t)bh << 22) + ((size_t)qi0 << 11);
  for (int g = tid; g < 64 * 512; g += 256) {
    const int row = g >> 9;
    const int j0 = (g & 511) << 2;
    const int local = j0 - ofs;
    f32x4 w = {0.f, 0.f, 0.f, 0.f};
    if ((unsigned)local < 320u) {
      bf16x4 p = *reinterpret_cast<const bf16x4*>(&Ps[row][local]);
      w[0] = (float)p[0]; w[1] = (float)p[1]; w[2] = (float)p[2]; w[3] = (float)p[3];
    }
    __builtin_nontemporal_store(w, reinterpret_cast<f32x4*>(tilebase + ((size_t)row << 11) + j0));
  }
}

// ---------------- launch ----------------
extern "C" void kernel_launch(void* const* d_in, const int* in_sizes, int n_in,
                              void* d_out, int out_size, void* d_ws, size_t ws_size,
                              hipStream_t stream) {
  const float* x = (const float*)d_in[0];      // (2,2048,512)
  const float* Wqkv = (const float*)d_in[1];   // (512,1536)
  const float* Wout = (const float*)d_in[2];   // (512,512)
  float* out = (float*)d_out;                  // (2,2048,512) f32
  float* attn = out + (size_t)2 * 2048 * 512;  // (2,8,2048,2048) f32

  char* ws = (char*)d_ws;
  __bf16* Wqt  = (__bf16*)(ws);                                // 1.5 MiB [1536][512]
  __bf16* Wot  = (__bf16*)(ws + 1572864);                      // 0.5 MiB [512][512]
  __bf16* QKVb = (__bf16*)(ws + 1572864 + 524288);             // 12 MiB  [4096][1536]
  __bf16* AOb  = (__bf16*)(ws + 1572864 + 524288 + 12582912);  // 4 MiB   [4096][512]

  prep<<<256, 256, 0, stream>>>(Wqkv, Wout, Wqt, Wot);

  // QKV = x @ Wqkv (4096 x 1536)
  gemm_bt<float, __bf16><<<dim3(12, 32), 256, 0, stream>>>(x, Wqt, QKVb, 4096, 1536, 512);

  // attn: each block computes and streams its full 64-row attn stripe
  attn_fused<<<dim3(32, 16), 256, 0, stream>>>(QKVb, attn, AOb);

  // out = AO @ Wout (4096 x 512)
  gemm_bt<__bf16, float><<<dim3(4, 32), 256, 0, stream>>>(AOb, Wot, out, 4096, 512, 512);
}

// Round 16
// 89.642 us; speedup vs baseline: 1.2393x; 1.2393x over previous
//
#include <hip/hip_runtime.h>
#include <hip/hip_bf16.h>

typedef __bf16 bf16x8 __attribute__((ext_vector_type(8)));
typedef float f32x4 __attribute__((ext_vector_type(4)));

#define MFMA16(a,b,c) __builtin_amdgcn_mfma_f32_16x16x32_bf16(a, b, c, 0, 0, 0)

// ---- zero-fill: rows [rowStart,rowEnd) of attn, outside the sliding band ----
// Cached (non-NT) stores: let L2/L3 absorb the zero stream instead of forcing
// direct HBM commit that serializes against compute-block reads.
__device__ inline void fill_attn_rows(float* __restrict__ attn, int rowStart, int rowEnd,
                                      int tid) {
  const f32x4 z4 = {0.f, 0.f, 0.f, 0.f};
  for (int g = rowStart; g < rowEnd; g++) {
    const int bh = g >> 11, i = g & 2047;
    const int qt = i >> 6;
    const int lo = qt >= 4 ? (qt - 4) << 6 : 0;
    const int hi = (qt + 1) << 6;
    float* rp = attn + ((size_t)bh << 22) + ((size_t)i << 11);
    for (int j = tid << 2; j < lo; j += 1024)
      *reinterpret_cast<f32x4*>(rp + j) = z4;
    for (int j = hi + (tid << 2); j < 2048; j += 1024)
      *reinterpret_cast<f32x4*>(rp + j) = z4;
  }
}

__device__ inline void fill_block_chunk(float* __restrict__ attn, int fillStart, int fillEnd,
                                        int fid, int nfill, int tid) {
  const int total = fillEnd - fillStart;
  const int per = (total + nfill - 1) / nfill;
  const int myStart = fillStart + fid * per;
  int myEnd = myStart + per;
  if (myEnd > fillEnd) myEnd = fillEnd;
  if (myStart < myEnd) fill_attn_rows(attn, myStart, myEnd, tid);
}

// ---------------- prep: transpose + cvt W_qkv, W_out ----------------
__device__ inline void transpose_body(const float* __restrict__ in, __bf16* __restrict__ out,
                                      int R, int C, int tile, int tid, float (*t)[65]) {
  const int tilesC = C >> 6;
  const int tc = tile % tilesC, tr = tile / tilesC;
  const int r0 = tr << 6, c0 = tc << 6;
  const int ri = tid >> 2, cq = (tid & 3) << 4;
#pragma unroll
  for (int e = 0; e < 16; e += 4) {
    float4 v = *reinterpret_cast<const float4*>(&in[(size_t)(r0 + ri) * C + c0 + cq + e]);
    t[ri][cq + e]     = v.x;
    t[ri][cq + e + 1] = v.y;
    t[ri][cq + e + 2] = v.z;
    t[ri][cq + e + 3] = v.w;
  }
  __syncthreads();
  const int co = tid >> 2, rq = (tid & 3) << 4;
  __attribute__((aligned(16))) __bf16 buf[16];
#pragma unroll
  for (int e = 0; e < 16; e++) buf[e] = (__bf16)t[rq + e][co];
  *reinterpret_cast<bf16x8*>(&out[(size_t)(c0 + co) * R + r0 + rq])     = *reinterpret_cast<bf16x8*>(&buf[0]);
  *reinterpret_cast<bf16x8*>(&out[(size_t)(c0 + co) * R + r0 + rq + 8]) = *reinterpret_cast<bf16x8*>(&buf[8]);
}

__global__ __launch_bounds__(256) void prep(const float* __restrict__ Wqkv,
                                            const float* __restrict__ Wout,
                                            __bf16* __restrict__ Wqt,
                                            __bf16* __restrict__ Wot) {
  __shared__ float t[64][65];
  const int bid = blockIdx.x, tid = threadIdx.x;
  if (bid < 192) transpose_body(Wqkv, Wqt, 512, 1536, bid, tid, t);
  else           transpose_body(Wout, Wot, 512, 512, bid - 192, tid, t);
}

// ---------------- GEMM: C[M][N] = A[M][K] * Bt[N][K]^T ----------------
// Blocks with blockIdx.x >= gxCompute are concurrent attn-zero-fill blocks.
template <typename AT, typename OT>
__global__ __launch_bounds__(256) void gemm_bt(const AT* __restrict__ A,
                                               const __bf16* __restrict__ Bt,
                                               OT* __restrict__ C, int M, int N, int K,
                                               float* __restrict__ fillAttn,
                                               int fillStart, int fillEnd, int gxCompute) {
  __shared__ __bf16 As[128][72];
  __shared__ __bf16 Bs[128][72];
  const int tid = threadIdx.x;

  if ((int)blockIdx.x >= gxCompute) {  // concurrent fill block
    const int nfx = gridDim.x - gxCompute;
    const int fid = (blockIdx.x - gxCompute) + nfx * blockIdx.y;
    fill_block_chunk(fillAttn, fillStart, fillEnd, fid, nfx * gridDim.y, tid);
    return;
  }

  const int wave = tid >> 6, lane = tid & 63;
  const int c = lane & 15, q4 = lane >> 4;
  const int bm = blockIdx.y << 7, bn = blockIdx.x << 7;
  const int wm = (wave >> 1) << 6, wn = (wave & 1) << 6;
  f32x4 acc[4][4];
#pragma unroll
  for (int m = 0; m < 4; m++)
#pragma unroll
    for (int n = 0; n < 4; n++)
#pragma unroll
      for (int e = 0; e < 4; e++) acc[m][n][e] = 0.f;

  const int srow = tid >> 1, scol = (tid & 1) << 5;
  bf16x8 av[4], bv[4];

  auto loadA = [&](int k0) {
    const AT* ag = A + (size_t)(bm + srow) * K + k0 + scol;
    if constexpr (sizeof(AT) == 4) {
#pragma unroll
      for (int r = 0; r < 4; r++) {
        float4 lo = *reinterpret_cast<const float4*>(ag + r * 8);
        float4 hi = *reinterpret_cast<const float4*>(ag + r * 8 + 4);
        bf16x8 v;
        v[0] = (__bf16)lo.x; v[1] = (__bf16)lo.y; v[2] = (__bf16)lo.z; v[3] = (__bf16)lo.w;
        v[4] = (__bf16)hi.x; v[5] = (__bf16)hi.y; v[6] = (__bf16)hi.z; v[7] = (__bf16)hi.w;
        av[r] = v;
      }
    } else {
#pragma unroll
      for (int r = 0; r < 4; r++) av[r] = *reinterpret_cast<const bf16x8*>(ag + r * 8);
    }
  };
  auto loadB = [&](int k0) {
    const __bf16* bg = Bt + (size_t)(bn + srow) * K + k0 + scol;
#pragma unroll
    for (int r = 0; r < 4; r++) bv[r] = *reinterpret_cast<const bf16x8*>(bg + r * 8);
  };

  loadA(0); loadB(0);
  for (int k0 = 0; k0 < K; k0 += 64) {
    __syncthreads();
#pragma unroll
    for (int r = 0; r < 4; r++) *reinterpret_cast<bf16x8*>(&As[srow][scol + r * 8]) = av[r];
#pragma unroll
    for (int r = 0; r < 4; r++) *reinterpret_cast<bf16x8*>(&Bs[srow][scol + r * 8]) = bv[r];
    __syncthreads();
    if (k0 + 64 < K) { loadA(k0 + 64); loadB(k0 + 64); }
#pragma unroll
    for (int ks = 0; ks < 2; ks++) {
      const int kk = ks * 32 + q4 * 8;
      bf16x8 af[4], bfv[4];
#pragma unroll
      for (int m = 0; m < 4; m++) af[m] = *reinterpret_cast<const bf16x8*>(&As[wm + m * 16 + c][kk]);
#pragma unroll
      for (int n = 0; n < 4; n++) bfv[n] = *reinterpret_cast<const bf16x8*>(&Bs[wn + n * 16 + c][kk]);
#pragma unroll
      for (int m = 0; m < 4; m++)
#pragma unroll
        for (int n = 0; n < 4; n++) acc[m][n] = MFMA16(af[m], bfv[n], acc[m][n]);
    }
  }
#pragma unroll
  for (int m = 0; m < 4; m++)
#pragma unroll
    for (int n = 0; n < 4; n++)
#pragma unroll
      for (int r2 = 0; r2 < 4; r2++) {
        const int row = bm + wm + m * 16 + q4 * 4 + r2;
        const int col = bn + wn + n * 16 + c;
        C[(size_t)row * N + col] = (OT)acc[m][n][r2];
      }
}

// -------- fused attention, wave-per-rowgroup: in-wave softmax (r13 structure) --------
// grid: (32+16 x, 16 y); blocks x>=32 fill rows [9000,25000).
__global__ __launch_bounds__(256) void attn_fused(const __bf16* __restrict__ QKV,
                                                  float* __restrict__ attn,
                                                  __bf16* __restrict__ AO) {
  __shared__ __align__(16) __bf16 KV[2][64][72];   // K tiles / V^T tiles, dbuf
  __shared__ __align__(16) __bf16 Pw[4][16][72];   // per-wave P tile (wave-private)
  const int tid = threadIdx.x;

  if (blockIdx.x >= 32) {  // concurrent fill block
    const int fid = (blockIdx.x - 32) + (gridDim.x - 32) * blockIdx.y;
    fill_block_chunk(attn, 9000, 25000, fid, (gridDim.x - 32) * gridDim.y, tid);
    return;
  }

  const int qt = blockIdx.x, bh = blockIdx.y;
  const int b = bh >> 3, h = bh & 7;
  const int qi0 = qt << 6;
  const int wave = tid >> 6, lane = tid & 63;
  const int c = lane & 15, q4 = lane >> 4;
  const int base = b * 2048;
  const int r = tid >> 2, qq = (tid & 3) << 4;

  // Q fragments direct to registers
  bf16x8 qf0, qf1;
  {
    const __bf16* s = QKV + (size_t)(base + qi0 + wave * 16 + c) * 1536 + h * 64 + q4 * 8;
    qf0 = *reinterpret_cast<const bf16x8*>(s);
    qf1 = *reinterpret_cast<const bf16x8*>(s + 32);
  }

  f32x4 acc[5][4];  // [t][ct]: rows w*16+q4*4+r2, cols (qt-4+t)*64 + ct*16 + c
#pragma unroll
  for (int t = 0; t < 5; t++)
#pragma unroll
    for (int ct = 0; ct < 4; ct++)
#pragma unroll
      for (int e = 0; e < 4; e++) acc[t][ct][e] = 0.f;

  const int tfirst = qt >= 4 ? 0 : 4 - qt;
  bf16x8 kv0, kv1;
  {  // prologue K load
    const __bf16* s = QKV + (size_t)(base + ((qt - 4 + tfirst) << 6) + r) * 1536 + 512 + h * 64 + qq;
    kv0 = *reinterpret_cast<const bf16x8*>(s);
    kv1 = *reinterpret_cast<const bf16x8*>(s + 8);
  }
  int cur = 0;
#pragma unroll
  for (int t = 0; t < 5; t++) {
    if (qt - 4 + t < 0) continue;  // block-uniform
    *reinterpret_cast<bf16x8*>(&KV[cur][r][qq]) = kv0;
    *reinterpret_cast<bf16x8*>(&KV[cur][r][qq + 8]) = kv1;
    if (t < 4) {  // prefetch next K tile; completes under MFMA
      const __bf16* s = QKV + (size_t)(base + ((qt - 3 + t) << 6) + r) * 1536 + 512 + h * 64 + qq;
      kv0 = *reinterpret_cast<const bf16x8*>(s);
      kv1 = *reinterpret_cast<const bf16x8*>(s + 8);
    }
    __syncthreads();
#pragma unroll
    for (int ks = 0; ks < 2; ks++) {
      const int kk = ks * 32 + q4 * 8;
      const bf16x8 af = ks ? qf1 : qf0;
#pragma unroll
      for (int ct = 0; ct < 4; ct++) {
        bf16x8 bfr = *reinterpret_cast<const bf16x8*>(&KV[cur][ct * 16 + c][kk]);
        acc[t][ct] = MFMA16(af, bfr, acc[t][ct]);
      }
    }
    cur ^= 1;
  }

  // mask + scale (in-register)
  const float scale = 0.125f;
  const int igBase = qi0 + wave * 16 + q4 * 4;
#pragma unroll
  for (int t = 0; t < 5; t++) {
#pragma unroll
    for (int ct = 0; ct < 4; ct++) {
      const int jb = ((qt - 4 + t) << 6) + ct * 16 + c;
#pragma unroll
      for (int r2 = 0; r2 < 4; r2++) {
        const int ig = igBase + r2;
        const bool valid = (jb >= 0) && (jb <= ig) && (jb >= ig - 255);
        acc[t][ct][r2] = valid ? acc[t][ct][r2] * scale : -1e30f;
      }
    }
  }

  // in-wave softmax (shfl_xor 8,4,2,1 within 16-lane groups)
  float pm[4];
#pragma unroll
  for (int r2 = 0; r2 < 4; r2++) {
    float v = acc[0][0][r2];
#pragma unroll
    for (int t = 0; t < 5; t++)
#pragma unroll
      for (int ct = 0; ct < 4; ct++) v = fmaxf(v, acc[t][ct][r2]);
    pm[r2] = v;
  }
#pragma unroll
  for (int off = 8; off >= 1; off >>= 1)
#pragma unroll
    for (int r2 = 0; r2 < 4; r2++) pm[r2] = fmaxf(pm[r2], __shfl_xor(pm[r2], off, 64));

  float ps[4] = {0.f, 0.f, 0.f, 0.f};
#pragma unroll
  for (int t = 0; t < 5; t++)
#pragma unroll
    for (int ct = 0; ct < 4; ct++)
#pragma unroll
      for (int r2 = 0; r2 < 4; r2++) {
        float p = __expf(acc[t][ct][r2] - pm[r2]);
        acc[t][ct][r2] = p;
        ps[r2] += p;
      }
#pragma unroll
  for (int off = 8; off >= 1; off >>= 1)
#pragma unroll
    for (int r2 = 0; r2 < 4; r2++) ps[r2] += __shfl_xor(ps[r2], off, 64);

#pragma unroll
  for (int r2 = 0; r2 < 4; r2++) ps[r2] = 1.0f / ps[r2];
#pragma unroll
  for (int t = 0; t < 5; t++)
#pragma unroll
    for (int ct = 0; ct < 4; ct++)
#pragma unroll
      for (int r2 = 0; r2 < 4; r2++) acc[t][ct][r2] *= ps[r2];

  __syncthreads();  // guard KV handoff: all QK reads done before PV staging overwrites

  // ---------------- PV phase: O = P @ V ----------------
  f32x4 o[4];
#pragma unroll
  for (int n = 0; n < 4; n++)
#pragma unroll
    for (int e = 0; e < 4; e++) o[n][e] = 0.f;

  const int jv = tid >> 2, dqa = tid & 3;
  bf16x8 vr0, vr1;
  {  // prologue V load
    const __bf16* s = QKV + (size_t)(base + ((qt - 4 + tfirst) << 6) + jv) * 1536 + 1024 + h * 64;
    vr0 = *reinterpret_cast<const bf16x8*>(s + dqa * 8);
    vr1 = *reinterpret_cast<const bf16x8*>(s + (dqa + 4) * 8);
  }
  int pcur = 0;
#pragma unroll
  for (int t = 0; t < 5; t++) {
    if (qt - 4 + t < 0) continue;
    // P tile -> wave-private LDS (same-wave, no barrier)
#pragma unroll
    for (int ct = 0; ct < 4; ct++)
#pragma unroll
      for (int r2 = 0; r2 < 4; r2++)
        Pw[wave][q4 * 4 + r2][ct * 16 + c] = (__bf16)acc[t][ct][r2];
    // V regs -> LDS transposed (shared)
#pragma unroll
    for (int e = 0; e < 8; e++) {
      KV[pcur][dqa * 8 + e][jv] = vr0[e];
      KV[pcur][(dqa + 4) * 8 + e][jv] = vr1[e];
    }
    if (t < 4) {  // prefetch next V tile
      const __bf16* s = QKV + (size_t)(base + ((qt - 3 + t) << 6) + jv) * 1536 + 1024 + h * 64;
      vr0 = *reinterpret_cast<const bf16x8*>(s + dqa * 8);
      vr1 = *reinterpret_cast<const bf16x8*>(s + (dqa + 4) * 8);
    }
    __syncthreads();
#pragma unroll
    for (int ks = 0; ks < 2; ks++) {
      const int kk = ks * 32 + q4 * 8;
      bf16x8 af = *reinterpret_cast<const bf16x8*>(&Pw[wave][c][kk]);
#pragma unroll
      for (int n = 0; n < 4; n++) {
        bf16x8 bfr = *reinterpret_cast<const bf16x8*>(&KV[pcur][n * 16 + c][kk]);
        o[n] = MFMA16(af, bfr, o[n]);
      }
    }
    pcur ^= 1;
  }

  // ---------------- global stores (after last barrier) ----------------
  // band: scalar cached stores ordered (r2, t, ct) for adjacent-segment L2 merging
  float* arow = attn + ((size_t)bh << 22);
#pragma unroll
  for (int r2 = 0; r2 < 4; r2++) {
    const int ig = igBase + r2;
    float* rowp = arow + ((size_t)ig << 11);
#pragma unroll
    for (int t = 0; t < 5; t++) {
      const int jt0 = (qt - 4 + t) << 6;
      if (jt0 < 0) continue;
#pragma unroll
      for (int ct = 0; ct < 4; ct++) {
        const int jb = jt0 + ct * 16 + c;
        rowp[jb] = acc[t][ct][r2];
      }
    }
  }

  // AO via wave-private Pw transpose: 2x bf16x8 per lane, 64B contiguous per 4-lane group
#pragma unroll
  for (int n = 0; n < 4; n++)
#pragma unroll
    for (int r2 = 0; r2 < 4; r2++)
      Pw[wave][q4 * 4 + r2][n * 16 + c] = (__bf16)o[n][r2];
  {
    const int er = lane >> 2;        // row 0..15 within wave's group
    const int ec = (lane & 3) << 4;  // col segment 0,16,32,48
    bf16x8 a0 = *reinterpret_cast<const bf16x8*>(&Pw[wave][er][ec]);
    bf16x8 a1 = *reinterpret_cast<const bf16x8*>(&Pw[wave][er][ec + 8]);
    __bf16* adst = AO + (size_t)(base + qi0 + wave * 16 + er) * 512 + h * 64 + ec;
    *reinterpret_cast<bf16x8*>(adst) = a0;
    *reinterpret_cast<bf16x8*>(adst + 8) = a1;
  }
}

// ---------------- launch ----------------
extern "C" void kernel_launch(void* const* d_in, const int* in_sizes, int n_in,
                              void* d_out, int out_size, void* d_ws, size_t ws_size,
                              hipStream_t stream) {
  const float* x = (const float*)d_in[0];      // (2,2048,512)
  const float* Wqkv = (const float*)d_in[1];   // (512,1536)
  const float* Wout = (const float*)d_in[2];   // (512,512)
  float* out = (float*)d_out;                  // (2,2048,512) f32
  float* attn = out + (size_t)2 * 2048 * 512;  // (2,8,2048,2048) f32

  char* ws = (char*)d_ws;
  __bf16* Wqt  = (__bf16*)(ws);                                // 1.5 MiB [1536][512]
  __bf16* Wot  = (__bf16*)(ws + 1572864);                      // 0.5 MiB [512][512]
  __bf16* QKVb = (__bf16*)(ws + 1572864 + 524288);             // 12 MiB  [4096][1536]
  __bf16* AOb  = (__bf16*)(ws + 1572864 + 524288 + 12582912);  // 4 MiB   [4096][512]

  prep<<<256, 256, 0, stream>>>(Wqkv, Wout, Wqt, Wot);

  // QKV = x @ Wqkv (4096x1536): 12x32 compute + 12x32 fill; rows [0,9000)
  gemm_bt<float, __bf16><<<dim3(24, 32), 256, 0, stream>>>(x, Wqt, QKVb, 4096, 1536, 512,
                                                           attn, 0, 9000, 12);

  // attn: 32x16 compute + 16x16 fill; rows [9000,25000)
  attn_fused<<<dim3(48, 16), 256, 0, stream>>>(QKVb, attn, AOb);

  // out = AO @ Wout (4096x512): 4x32 compute + 8x32 fill; rows [25000,32768)
  gemm_bt<__bf16, float><<<dim3(12, 32), 256, 0, stream>>>(AOb, Wot, out, 4096, 512, 512,
                                                           attn, 25000, 32768, 4);
}

// Round 17
// 83.897 us; speedup vs baseline: 1.3242x; 1.0685x over previous
//
#include <hip/hip_runtime.h>
#include <hip/hip_bf16.h>

typedef __bf16 bf16x8 __attribute__((ext_vector_type(8)));
typedef float f32x4 __attribute__((ext_vector_type(4)));

#define MFMA16(a,b,c) __builtin_amdgcn_mfma_f32_16x16x32_bf16(a, b, c, 0, 0, 0)

// ---- zero-fill: rows [rowStart,rowEnd) of attn, outside the sliding band (NT stores) ----
__device__ inline void fill_attn_rows(float* __restrict__ attn, int rowStart, int rowEnd,
                                      int tid) {
  const f32x4 z4 = {0.f, 0.f, 0.f, 0.f};
  for (int g = rowStart; g < rowEnd; g++) {
    const int bh = g >> 11, i = g & 2047;
    const int qt = i >> 6;
    const int lo = qt >= 4 ? (qt - 4) << 6 : 0;
    const int hi = (qt + 1) << 6;
    float* rp = attn + ((size_t)bh << 22) + ((size_t)i << 11);
    for (int j = tid << 2; j < lo; j += 1024)
      __builtin_nontemporal_store(z4, reinterpret_cast<f32x4*>(rp + j));
    for (int j = hi + (tid << 2); j < 2048; j += 1024)
      __builtin_nontemporal_store(z4, reinterpret_cast<f32x4*>(rp + j));
  }
}

__device__ inline void fill_block_chunk(float* __restrict__ attn, int fillStart, int fillEnd,
                                        int fid, int nfill, int tid) {
  const int total = fillEnd - fillStart;
  const int per = (total + nfill - 1) / nfill;
  const int myStart = fillStart + fid * per;
  int myEnd = myStart + per;
  if (myEnd > fillEnd) myEnd = fillEnd;
  if (myStart < myEnd) fill_attn_rows(attn, myStart, myEnd, tid);
}

// ---------------- prep: transpose + cvt W_qkv, W_out ----------------
__device__ inline void transpose_body(const float* __restrict__ in, __bf16* __restrict__ out,
                                      int R, int C, int tile, int tid, float (*t)[65]) {
  const int tilesC = C >> 6;
  const int tc = tile % tilesC, tr = tile / tilesC;
  const int r0 = tr << 6, c0 = tc << 6;
  const int ri = tid >> 2, cq = (tid & 3) << 4;
#pragma unroll
  for (int e = 0; e < 16; e += 4) {
    float4 v = *reinterpret_cast<const float4*>(&in[(size_t)(r0 + ri) * C + c0 + cq + e]);
    t[ri][cq + e]     = v.x;
    t[ri][cq + e + 1] = v.y;
    t[ri][cq + e + 2] = v.z;
    t[ri][cq + e + 3] = v.w;
  }
  __syncthreads();
  const int co = tid >> 2, rq = (tid & 3) << 4;
  __attribute__((aligned(16))) __bf16 buf[16];
#pragma unroll
  for (int e = 0; e < 16; e++) buf[e] = (__bf16)t[rq + e][co];
  *reinterpret_cast<bf16x8*>(&out[(size_t)(c0 + co) * R + r0 + rq])     = *reinterpret_cast<bf16x8*>(&buf[0]);
  *reinterpret_cast<bf16x8*>(&out[(size_t)(c0 + co) * R + r0 + rq + 8]) = *reinterpret_cast<bf16x8*>(&buf[8]);
}

__global__ __launch_bounds__(256) void prep(const float* __restrict__ Wqkv,
                                            const float* __restrict__ Wout,
                                            __bf16* __restrict__ Wqt,
                                            __bf16* __restrict__ Wot) {
  __shared__ float t[64][65];
  const int bid = blockIdx.x, tid = threadIdx.x;
  if (bid < 192) transpose_body(Wqkv, Wqt, 512, 1536, bid, tid, t);
  else           transpose_body(Wout, Wot, 512, 512, bid - 192, tid, t);
}

// ---------------- GEMM: C[M][N] = A[M][K] * Bt[N][K]^T ----------------
// Blocks with blockIdx.x >= gxCompute are concurrent attn-zero-fill blocks.
template <typename AT, typename OT>
__global__ __launch_bounds__(256) void gemm_bt(const AT* __restrict__ A,
                                               const __bf16* __restrict__ Bt,
                                               OT* __restrict__ C, int M, int N, int K,
                                               float* __restrict__ fillAttn,
                                               int fillStart, int fillEnd, int gxCompute) {
  __shared__ __bf16 As[128][72];
  __shared__ __bf16 Bs[128][72];
  const int tid = threadIdx.x;

  if ((int)blockIdx.x >= gxCompute) {  // concurrent fill block
    const int nfx = gridDim.x - gxCompute;
    const int fid = (blockIdx.x - gxCompute) + nfx * blockIdx.y;
    fill_block_chunk(fillAttn, fillStart, fillEnd, fid, nfx * gridDim.y, tid);
    return;
  }

  const int wave = tid >> 6, lane = tid & 63;
  const int c = lane & 15, q4 = lane >> 4;
  const int bm = blockIdx.y << 7, bn = blockIdx.x << 7;
  const int wm = (wave >> 1) << 6, wn = (wave & 1) << 6;
  f32x4 acc[4][4];
#pragma unroll
  for (int m = 0; m < 4; m++)
#pragma unroll
    for (int n = 0; n < 4; n++)
#pragma unroll
      for (int e = 0; e < 4; e++) acc[m][n][e] = 0.f;

  const int srow = tid >> 1, scol = (tid & 1) << 5;
  bf16x8 av[4], bv[4];

  auto loadA = [&](int k0) {
    const AT* ag = A + (size_t)(bm + srow) * K + k0 + scol;
    if constexpr (sizeof(AT) == 4) {
#pragma unroll
      for (int r = 0; r < 4; r++) {
        float4 lo = *reinterpret_cast<const float4*>(ag + r * 8);
        float4 hi = *reinterpret_cast<const float4*>(ag + r * 8 + 4);
        bf16x8 v;
        v[0] = (__bf16)lo.x; v[1] = (__bf16)lo.y; v[2] = (__bf16)lo.z; v[3] = (__bf16)lo.w;
        v[4] = (__bf16)hi.x; v[5] = (__bf16)hi.y; v[6] = (__bf16)hi.z; v[7] = (__bf16)hi.w;
        av[r] = v;
      }
    } else {
#pragma unroll
      for (int r = 0; r < 4; r++) av[r] = *reinterpret_cast<const bf16x8*>(ag + r * 8);
    }
  };
  auto loadB = [&](int k0) {
    const __bf16* bg = Bt + (size_t)(bn + srow) * K + k0 + scol;
#pragma unroll
    for (int r = 0; r < 4; r++) bv[r] = *reinterpret_cast<const bf16x8*>(bg + r * 8);
  };

  loadA(0); loadB(0);
  for (int k0 = 0; k0 < K; k0 += 64) {
    __syncthreads();
#pragma unroll
    for (int r = 0; r < 4; r++) *reinterpret_cast<bf16x8*>(&As[srow][scol + r * 8]) = av[r];
#pragma unroll
    for (int r = 0; r < 4; r++) *reinterpret_cast<bf16x8*>(&Bs[srow][scol + r * 8]) = bv[r];
    __syncthreads();
    if (k0 + 64 < K) { loadA(k0 + 64); loadB(k0 + 64); }
#pragma unroll
    for (int ks = 0; ks < 2; ks++) {
      const int kk = ks * 32 + q4 * 8;
      bf16x8 af[4], bfv[4];
#pragma unroll
      for (int m = 0; m < 4; m++) af[m] = *reinterpret_cast<const bf16x8*>(&As[wm + m * 16 + c][kk]);
#pragma unroll
      for (int n = 0; n < 4; n++) bfv[n] = *reinterpret_cast<const bf16x8*>(&Bs[wn + n * 16 + c][kk]);
#pragma unroll
      for (int m = 0; m < 4; m++)
#pragma unroll
        for (int n = 0; n < 4; n++) acc[m][n] = MFMA16(af[m], bfv[n], acc[m][n]);
    }
  }
#pragma unroll
  for (int m = 0; m < 4; m++)
#pragma unroll
    for (int n = 0; n < 4; n++)
#pragma unroll
      for (int r2 = 0; r2 < 4; r2++) {
        const int row = bm + wm + m * 16 + q4 * 4 + r2;
        const int col = bn + wn + n * 16 + c;
        C[(size_t)row * N + col] = (OT)acc[m][n][r2];
      }
}

// -------- fused attention, wave-per-rowgroup, XCD-aware (qt,bh) remap --------
// grid: (32+16 x, 16 y); blocks x>=32 fill rows [9000,25000).
// Compute blocks: lin = y*32+x; bh = lin&15, qt = lin>>4  => each XCD serves 2 heads,
// all q-tiles -> K/V tiles reused within the XCD's L2.
__global__ __launch_bounds__(256) void attn_fused(const __bf16* __restrict__ QKV,
                                                  float* __restrict__ attn,
                                                  __bf16* __restrict__ AO) {
  __shared__ __align__(16) __bf16 KV[2][64][72];   // K tiles / V^T tiles, dbuf
  __shared__ __align__(16) __bf16 Pw[4][16][72];   // per-wave P tile (wave-private)
  const int tid = threadIdx.x;

  if (blockIdx.x >= 32) {  // concurrent fill block
    const int fid = (blockIdx.x - 32) + (gridDim.x - 32) * blockIdx.y;
    fill_block_chunk(attn, 9000, 25000, fid, (gridDim.x - 32) * gridDim.y, tid);
    return;
  }

  const int lin = blockIdx.y * 32 + blockIdx.x;
  const int qt = lin >> 4, bh = lin & 15;
  const int b = bh >> 3, h = bh & 7;
  const int qi0 = qt << 6;
  const int wave = tid >> 6, lane = tid & 63;
  const int c = lane & 15, q4 = lane >> 4;
  const int base = b * 2048;
  const int r = tid >> 2, qq = (tid & 3) << 4;

  // Q fragments direct to registers
  bf16x8 qf0, qf1;
  {
    const __bf16* s = QKV + (size_t)(base + qi0 + wave * 16 + c) * 1536 + h * 64 + q4 * 8;
    qf0 = *reinterpret_cast<const bf16x8*>(s);
    qf1 = *reinterpret_cast<const bf16x8*>(s + 32);
  }

  f32x4 acc[5][4];  // [t][ct]: rows w*16+q4*4+r2, cols (qt-4+t)*64 + ct*16 + c
#pragma unroll
  for (int t = 0; t < 5; t++)
#pragma unroll
    for (int ct = 0; ct < 4; ct++)
#pragma unroll
      for (int e = 0; e < 4; e++) acc[t][ct][e] = 0.f;

  const int tfirst = qt >= 4 ? 0 : 4 - qt;
  bf16x8 kv0, kv1;
  {  // prologue K load
    const __bf16* s = QKV + (size_t)(base + ((qt - 4 + tfirst) << 6) + r) * 1536 + 512 + h * 64 + qq;
    kv0 = *reinterpret_cast<const bf16x8*>(s);
    kv1 = *reinterpret_cast<const bf16x8*>(s + 8);
  }
  int cur = 0;
#pragma unroll
  for (int t = 0; t < 5; t++) {
    if (qt - 4 + t < 0) continue;  // block-uniform
    *reinterpret_cast<bf16x8*>(&KV[cur][r][qq]) = kv0;
    *reinterpret_cast<bf16x8*>(&KV[cur][r][qq + 8]) = kv1;
    if (t < 4) {  // prefetch next K tile; completes under MFMA
      const __bf16* s = QKV + (size_t)(base + ((qt - 3 + t) << 6) + r) * 1536 + 512 + h * 64 + qq;
      kv0 = *reinterpret_cast<const bf16x8*>(s);
      kv1 = *reinterpret_cast<const bf16x8*>(s + 8);
    }
    __syncthreads();
#pragma unroll
    for (int ks = 0; ks < 2; ks++) {
      const int kk = ks * 32 + q4 * 8;
      const bf16x8 af = ks ? qf1 : qf0;
#pragma unroll
      for (int ct = 0; ct < 4; ct++) {
        bf16x8 bfr = *reinterpret_cast<const bf16x8*>(&KV[cur][ct * 16 + c][kk]);
        acc[t][ct] = MFMA16(af, bfr, acc[t][ct]);
      }
    }
    cur ^= 1;
  }

  // mask + scale (in-register)
  const float scale = 0.125f;
  const int igBase = qi0 + wave * 16 + q4 * 4;
#pragma unroll
  for (int t = 0; t < 5; t++) {
#pragma unroll
    for (int ct = 0; ct < 4; ct++) {
      const int jb = ((qt - 4 + t) << 6) + ct * 16 + c;
#pragma unroll
      for (int r2 = 0; r2 < 4; r2++) {
        const int ig = igBase + r2;
        const bool valid = (jb >= 0) && (jb <= ig) && (jb >= ig - 255);
        acc[t][ct][r2] = valid ? acc[t][ct][r2] * scale : -1e30f;
      }
    }
  }

  // in-wave softmax (shfl_xor 8,4,2,1 within 16-lane groups)
  float pm[4];
#pragma unroll
  for (int r2 = 0; r2 < 4; r2++) {
    float v = acc[0][0][r2];
#pragma unroll
    for (int t = 0; t < 5; t++)
#pragma unroll
      for (int ct = 0; ct < 4; ct++) v = fmaxf(v, acc[t][ct][r2]);
    pm[r2] = v;
  }
#pragma unroll
  for (int off = 8; off >= 1; off >>= 1)
#pragma unroll
    for (int r2 = 0; r2 < 4; r2++) pm[r2] = fmaxf(pm[r2], __shfl_xor(pm[r2], off, 64));

  float ps[4] = {0.f, 0.f, 0.f, 0.f};
#pragma unroll
  for (int t = 0; t < 5; t++)
#pragma unroll
    for (int ct = 0; ct < 4; ct++)
#pragma unroll
      for (int r2 = 0; r2 < 4; r2++) {
        float p = __expf(acc[t][ct][r2] - pm[r2]);
        acc[t][ct][r2] = p;
        ps[r2] += p;
      }
#pragma unroll
  for (int off = 8; off >= 1; off >>= 1)
#pragma unroll
    for (int r2 = 0; r2 < 4; r2++) ps[r2] += __shfl_xor(ps[r2], off, 64);

#pragma unroll
  for (int r2 = 0; r2 < 4; r2++) ps[r2] = 1.0f / ps[r2];
#pragma unroll
  for (int t = 0; t < 5; t++)
#pragma unroll
    for (int ct = 0; ct < 4; ct++)
#pragma unroll
      for (int r2 = 0; r2 < 4; r2++) acc[t][ct][r2] *= ps[r2];

  __syncthreads();  // guard KV handoff: all QK reads done before PV staging overwrites

  // ---------------- PV phase: O = P @ V ----------------
  f32x4 o[4];
#pragma unroll
  for (int n = 0; n < 4; n++)
#pragma unroll
    for (int e = 0; e < 4; e++) o[n][e] = 0.f;

  const int jv = tid >> 2, dqa = tid & 3;
  bf16x8 vr0, vr1;
  {  // prologue V load
    const __bf16* s = QKV + (size_t)(base + ((qt - 4 + tfirst) << 6) + jv) * 1536 + 1024 + h * 64;
    vr0 = *reinterpret_cast<const bf16x8*>(s + dqa * 8);
    vr1 = *reinterpret_cast<const bf16x8*>(s + (dqa + 4) * 8);
  }
  int pcur = 0;
#pragma unroll
  for (int t = 0; t < 5; t++) {
    if (qt - 4 + t < 0) continue;
    // P tile -> wave-private LDS (same-wave, no barrier)
#pragma unroll
    for (int ct = 0; ct < 4; ct++)
#pragma unroll
      for (int r2 = 0; r2 < 4; r2++)
        Pw[wave][q4 * 4 + r2][ct * 16 + c] = (__bf16)acc[t][ct][r2];
    // V regs -> LDS transposed (shared)
#pragma unroll
    for (int e = 0; e < 8; e++) {
      KV[pcur][dqa * 8 + e][jv] = vr0[e];
      KV[pcur][(dqa + 4) * 8 + e][jv] = vr1[e];
    }
    if (t < 4) {  // prefetch next V tile
      const __bf16* s = QKV + (size_t)(base + ((qt - 3 + t) << 6) + jv) * 1536 + 1024 + h * 64;
      vr0 = *reinterpret_cast<const bf16x8*>(s + dqa * 8);
      vr1 = *reinterpret_cast<const bf16x8*>(s + (dqa + 4) * 8);
    }
    __syncthreads();
#pragma unroll
    for (int ks = 0; ks < 2; ks++) {
      const int kk = ks * 32 + q4 * 8;
      bf16x8 af = *reinterpret_cast<const bf16x8*>(&Pw[wave][c][kk]);
#pragma unroll
      for (int n = 0; n < 4; n++) {
        bf16x8 bfr = *reinterpret_cast<const bf16x8*>(&KV[pcur][n * 16 + c][kk]);
        o[n] = MFMA16(af, bfr, o[n]);
      }
    }
    pcur ^= 1;
  }

  // ---------------- global stores (after last barrier) ----------------
  // band: scalar cached stores ordered (r2, t, ct) for adjacent-segment L2 merging
  float* arow = attn + ((size_t)bh << 22);
#pragma unroll
  for (int r2 = 0; r2 < 4; r2++) {
    const int ig = igBase + r2;
    float* rowp = arow + ((size_t)ig << 11);
#pragma unroll
    for (int t = 0; t < 5; t++) {
      const int jt0 = (qt - 4 + t) << 6;
      if (jt0 < 0) continue;
#pragma unroll
      for (int ct = 0; ct < 4; ct++) {
        const int jb = jt0 + ct * 16 + c;
        rowp[jb] = acc[t][ct][r2];
      }
    }
  }

  // AO via wave-private Pw transpose: 2x bf16x8 per lane, 64B contiguous per 4-lane group
#pragma unroll
  for (int n = 0; n < 4; n++)
#pragma unroll
    for (int r2 = 0; r2 < 4; r2++)
      Pw[wave][q4 * 4 + r2][n * 16 + c] = (__bf16)o[n][r2];
  {
    const int er = lane >> 2;        // row 0..15 within wave's group
    const int ec = (lane & 3) << 4;  // col segment 0,16,32,48
    bf16x8 a0 = *reinterpret_cast<const bf16x8*>(&Pw[wave][er][ec]);
    bf16x8 a1 = *reinterpret_cast<const bf16x8*>(&Pw[wave][er][ec + 8]);
    __bf16* adst = AO + (size_t)(base + qi0 + wave * 16 + er) * 512 + h * 64 + ec;
    *reinterpret_cast<bf16x8*>(adst) = a0;
    *reinterpret_cast<bf16x8*>(adst + 8) = a1;
  }
}

// ---------------- launch ----------------
extern "C" void kernel_launch(void* const* d_in, const int* in_sizes, int n_in,
                              void* d_out, int out_size, void* d_ws, size_t ws_size,
                              hipStream_t stream) {
  const float* x = (const float*)d_in[0];      // (2,2048,512)
  const float* Wqkv = (const float*)d_in[1];   // (512,1536)
  const float* Wout = (const float*)d_in[2];   // (512,512)
  float* out = (float*)d_out;                  // (2,2048,512) f32
  float* attn = out + (size_t)2 * 2048 * 512;  // (2,8,2048,2048) f32

  char* ws = (char*)d_ws;
  __bf16* Wqt  = (__bf16*)(ws);                                // 1.5 MiB [1536][512]
  __bf16* Wot  = (__bf16*)(ws + 1572864);                      // 0.5 MiB [512][512]
  __bf16* QKVb = (__bf16*)(ws + 1572864 + 524288);             // 12 MiB  [4096][1536]
  __bf16* AOb  = (__bf16*)(ws + 1572864 + 524288 + 12582912);  // 4 MiB   [4096][512]

  prep<<<256, 256, 0, stream>>>(Wqkv, Wout, Wqt, Wot);

  // QKV = x @ Wqkv (4096x1536): 12x32 compute + 12x32 fill; rows [0,9000)
  gemm_bt<float, __bf16><<<dim3(24, 32), 256, 0, stream>>>(x, Wqt, QKVb, 4096, 1536, 512,
                                                           attn, 0, 9000, 12);

  // attn: 32x16 compute (XCD-remapped) + 16x16 fill; rows [9000,25000)
  attn_fused<<<dim3(48, 16), 256, 0, stream>>>(QKVb, attn, AOb);

  // out = AO @ Wout (4096x512): 4x32 compute + 8x32 fill; rows [25000,32768)
  gemm_bt<__bf16, float><<<dim3(12, 32), 256, 0, stream>>>(AOb, Wot, out, 4096, 512, 512,
                                                           attn, 25000, 32768, 4);
}